// Round 11
// baseline (818.612 us; speedup 1.0000x reference)
//
#include <hip/hip_runtime.h>
#include <stdint.h>

typedef unsigned int u32;
typedef unsigned long long u64;
typedef unsigned short u16b;
typedef __attribute__((ext_vector_type(8))) short short8;   // 8 bf16 = 4 VGPR (MFMA A/B frag)
typedef __attribute__((ext_vector_type(4))) float v4f;      // MFMA C/D frag

constexpr int NP = 16384;   // points per batch
// ---- fixed float-region offsets (in floats) ----
constexpr int W0T = 0;        // [8][64]
constexpr int W1T = 512;      // [64][64]
constexpr int W2T = 4608;     // [64][64]
constexpr int W3T = 8704;     // [64][128]
constexpr int B0F = 16896, B1F = 16960, B2F = 17024, B3F = 17088, B4F = 17216;
constexpr int GFO = 18240;    // gf  [16][1024]
constexpr int GCFO = 34624;   // gcf [4][1024]
constexpr int OF1O = 38720;   // of1 [16][512]
constexpr int GR1O = 46912;   // gr1 [512]
constexpr int FIXED_FLOATS = 47424;
constexpr u32 FIXED_BYTES = FIXED_FLOATS * 4;   // 189696 B

struct __align__(16) f4 { float x, y, z, w; };

__device__ __forceinline__ u16b f2bf(float f){
  u32 u = __float_as_uint(f);
  return (u16b)((u + 0x7FFFu + ((u >> 16) & 1u)) >> 16);   // RNE
}
__device__ __forceinline__ float bfu(u16b h){ return __uint_as_float(((u32)h) << 16); }

// exact-cascade 3-way bf16 split: x ~= hi+mid+lo to ~27 bits
__device__ __forceinline__ void split3(float x, u16b& h, u16b& m, u16b& l){
  h = f2bf(x);           float r1 = x - bfu(h);
  m = f2bf(r1);          float r2 = r1 - bfu(m);
  l = f2bf(r2);
}

__device__ __forceinline__ void fma4(f4& c, float s, const f4& a){
  c.x = fmaf(s, a.x, c.x); c.y = fmaf(s, a.y, c.y);
  c.z = fmaf(s, a.z, c.z); c.w = fmaf(s, a.w, c.w);
}

// ---------------- prep: transpose L0-3 weights; split+frag-pack W5 to bf16x3 ----------------
// Wb layout (bf16): [s][kc][nt][lane][j]  addr = s*131072 + kc*32768 + nt*512 + L*8 + j
__global__ __launch_bounds__(256) void k_prep(
    const float* __restrict__ wl0, const float* __restrict__ wl1, const float* __restrict__ wl2,
    const float* __restrict__ wl3, const float* __restrict__ wl4,
    const float* __restrict__ bl0, const float* __restrict__ bl1, const float* __restrict__ bl2,
    const float* __restrict__ bl3, const float* __restrict__ bl4,
    float* __restrict__ wsf, u32 pmax_off, u32 gmax_off, u32 wb_off, int P, int G)
{
  int tid = blockIdx.x * 256 + threadIdx.x;            // grid 1024 -> 262144 threads
  u64* pmax = (u64*)((char*)wsf + pmax_off);
  u32* gmax = (u32*)((char*)wsf + gmax_off);
  if (tid < P * 16384) pmax[tid] = 0ull;
  if (tid < G * 4096)  gmax[tid] = 0u;
  if (tid < 131072){                                   // W5 split -> Wb
    int ch = tid >> 7, k = tid & 127;
    float x = wl4[tid];                                // wl4[ch*128 + k]
    u16b h, m, l; split3(x, h, m, l);
    int kc = k >> 5, q = (k >> 3) & 3, j = k & 7, nt = ch >> 4;
    u32 base = (u32)kc*32768u + (u32)nt*512u + (u32)(((ch & 15) | (q << 4)) * 8 + j);
    u16b* wb = (u16b*)((char*)wsf + wb_off);
    wb[base] = h; wb[131072u + base] = m; wb[262144u + base] = l;
  }
  if (tid < 512){ int k = tid >> 6, o = tid & 63;
    wsf[W0T + tid] = (k < 7) ? wl0[o*7 + k] : 0.f; }
  if (tid < 4096){ int k = tid >> 6, o = tid & 63;  wsf[W1T + tid] = wl1[o*64 + k]; }
  if (tid < 4096){ int k = tid >> 6, o = tid & 63;  wsf[W2T + tid] = wl2[o*64 + k]; }
  if (tid < 8192){ int k = tid >> 7, o = tid & 127; wsf[W3T + tid] = wl3[o*64 + k]; }
  if (tid < 64)   wsf[B0F + tid] = bl0[tid];
  if (tid < 64)   wsf[B1F + tid] = bl1[tid];
  if (tid < 64)   wsf[B2F + tid] = bl2[tid];
  if (tid < 128)  wsf[B3F + tid] = bl3[tid];
  if (tid < 1024) wsf[B4F + tid] = bl4[tid];
}

// 4pt x 4ch micro-tile for layers 0..3 (acts from LDS, weights from L2-resident ws)
template<int K, int OSTR>
__device__ __forceinline__ void gemm4(const float* Ain, const float* __restrict__ Wt,
                                      int pt4, int o4, f4 (&acc)[4])
{
  #pragma unroll
  for (int oi = 0; oi < 4; ++oi) acc[oi] = f4{0.f,0.f,0.f,0.f};
  #pragma unroll 4
  for (int k = 0; k < K; ++k){
    f4 a = *(const f4*)(Ain + k*64 + pt4);
    f4 w = *(const f4*)(Wt + k*OSTR + o4);
    fma4(acc[0], w.x, a); fma4(acc[1], w.y, a);
    fma4(acc[2], w.z, a); fma4(acc[3], w.w, a);
  }
}

__device__ __forceinline__ void epi4(const f4 (&acc)[4], const float* __restrict__ bias,
                                     int o4, float* out, int pt4)
{
  #pragma unroll
  for (int oi = 0; oi < 4; ++oi){
    float bb = bias[o4 + oi];
    f4 v = acc[oi];
    v.x = fmaxf(v.x + bb, 0.f); v.y = fmaxf(v.y + bb, 0.f);
    v.z = fmaxf(v.z + bb, 0.f); v.w = fmaxf(v.w + bb, 0.f);
    *(f4*)(out + (o4 + oi)*64 + pt4) = v;
  }
}

// split3 + frag-store of one L3 output half into F4 (LDS). Slot swizzle S = Lf ^ m.
template<int H>
__device__ __forceinline__ void storeF4(u16b* F4, const f4 (&acc)[4],
                                        int o4, int pt4, const float* __restrict__ wsf)
{
  const int kbase = o4 + 64*H;
  const int kc = kbase >> 5, q = (kbase >> 3) & 3, j0 = kbase & 7;
  #pragma unroll
  for (int jj = 0; jj < 4; ++jj){
    int pt = pt4 + jj;
    int m = pt >> 4, Lf = (pt & 15) | (q << 4);
    int SLf = Lf ^ m;                       // ^m swizzle (bank-spreading)
    u16b hh[4], mm[4], ll[4];
    #pragma unroll
    for (int oi = 0; oi < 4; ++oi){
      float v = fmaxf(((const float*)&acc[oi])[jj] + wsf[B3F + kbase + oi], 0.f);
      split3(v, hh[oi], mm[oi], ll[oi]);
    }
    u32 base = (u32)((m*4 + kc)*512 + SLf*8 + j0);
    #pragma unroll
    for (int s = 0; s < 3; ++s){
      const u16b* src = (s == 0) ? hh : (s == 1) ? mm : ll;
      uint2 pk;
      pk.x = (u32)src[0] | ((u32)src[1] << 16);
      pk.y = (u32)src[2] | ((u32)src[3] << 16);
      *(uint2*)(F4 + (u32)s*8192u + base) = pk;
    }
  }
}

// shared front section: stage A0, group masks, L0-3, split3 -> F4 in LDS.
// Returns with F4 ready (post s6). gmS stable after s2.
__device__ __forceinline__ void front_phase(const float* __restrict__ pts,
    const float* __restrict__ wsf, float* sB, u64* gmS,
    int b, int n0, int t, int pt4, int o4)
{
  if (t < 4) gmS[t] = 0ull;
  for (int e = t; e < 7*64; e += 256)
    sB[e] = pts[(b*7 + (e >> 6))*NP + n0 + (e & 63)];
  __syncthreads();   // s1
  if (t < 64){
    float v = sB[3*64 + t]; int gi = 0;
    float u1 = sB[4*64 + t]; if (u1 > v){ v = u1; gi = 1; }
    float u2 = sB[5*64 + t]; if (u2 > v){ v = u2; gi = 2; }
    float u3 = sB[6*64 + t]; if (u3 > v){ v = u3; gi = 3; }
    atomicOr(&gmS[gi], 1ull << t);
  }
  f4 acc4[4];
  gemm4<7,64>(sB, wsf + W0T, pt4, o4, acc4);
  epi4(acc4, wsf + B0F, o4, sB + 512, pt4);
  __syncthreads();   // s2 (A1 ready + masks done)
  gemm4<64,64>(sB + 512, wsf + W1T, pt4, o4, acc4);  epi4(acc4, wsf + B1F, o4, sB + 4608, pt4);
  __syncthreads();   // s3
  gemm4<64,64>(sB + 4608, wsf + W2T, pt4, o4, acc4); epi4(acc4, wsf + B2F, o4, sB + 512, pt4);
  __syncthreads();   // s4
  f4 acc4b[4];
  gemm4<64,128>(sB + 512, wsf + W3T, pt4, o4, acc4);
  gemm4<64,128>(sB + 512, wsf + W3T, pt4, o4 + 64, acc4b);
  __syncthreads();   // s5
  u16b* F4 = (u16b*)sB;
  storeF4<0>(F4, acc4,  o4, pt4, wsf);
  storeF4<1>(F4, acc4b, o4, pt4, wsf);
  __syncthreads();   // s6 (F4 ready)
}

// ================= FUSED PATH (r10, proven: 644 us) =================
__global__ __launch_bounds__(256, 2) void k_main(const float* __restrict__ pts,
    const float* __restrict__ wsf,
    const u16b* __restrict__ wb,
    u64* __restrict__ pmax, u32* __restrict__ gmax,
    int pmask, int gmask)
{
  __shared__ __align__(16) float sB[12288];    // 49152 B
  const int t = threadIdx.x;
  const int b = blockIdx.x >> 8;
  const int tile = blockIdx.x & 255;
  const int n0 = tile * 64;
  const int ptg = t & 15, pt4 = ptg << 2;
  const int o4 = (t >> 4) << 2;
  const int w = t >> 6;
  const int L = t & 63;
  const int qb = (L >> 4) << 2;

  u64* gmS = (u64*)(sB + 448);
  front_phase(pts, wsf, sB, gmS, b, n0, t, pt4, o4);

  // ggpack built after s2 (gmS stable; sB[448..463] untouched until s5, but gmS was
  // read into regs inside front... re-read here is fine only BEFORE s5 — so capture now
  // is invalid post-s6. Instead gmS region was overwritten by F4. -> capture BEFORE front?
  // r10 captured between s2 and s3; replicate: we re-load from gmS is NOT possible now.
  // Solution: ggpack recomputed from gmS copy staged in registers inside front is complex;
  // keep r10 exact behavior by reading gmS into regs before F4 overwrite:
  // (front_phase returns post-s6; so we saved gmS to regs via shared capture below)
  // NOTE: see k_main2 comment; here we inline the original r10 body instead.
  // ---- this path is never reached; real fused body below in k_main_r10 ----
  (void)w; (void)qb; (void)pmax; (void)gmax; (void)pmask; (void)gmask; (void)wb; (void)L;
}

// r10 fused kernel, verbatim structure (ggpack captured between s2 and s3)
__global__ __launch_bounds__(256, 2) void k_main_r10(const float* __restrict__ pts,
    const float* __restrict__ wsf,
    const u16b* __restrict__ wb,
    u64* __restrict__ pmax, u32* __restrict__ gmax,
    int pmask, int gmask)
{
  __shared__ __align__(16) float sB[12288];    // 49152 B
  const int t = threadIdx.x;
  const int b = blockIdx.x >> 8;
  const int tile = blockIdx.x & 255;
  const int n0 = tile * 64;
  const int ptg = t & 15, pt4 = ptg << 2;
  const int chg = t >> 4;
  const int o4 = chg << 2;
  const int w = t >> 6;
  const int L = t & 63;
  const int qb = (L >> 4) << 2;

  u64* gmS = (u64*)(sB + 448);
  if (t < 4) gmS[t] = 0ull;
  for (int e = t; e < 7*64; e += 256)
    sB[e] = pts[(b*7 + (e >> 6))*NP + n0 + (e & 63)];
  __syncthreads();   // s1

  if (t < 64){
    float v = sB[3*64 + t]; int gi = 0;
    float u1 = sB[4*64 + t]; if (u1 > v){ v = u1; gi = 1; }
    float u2 = sB[5*64 + t]; if (u2 > v){ v = u2; gi = 2; }
    float u3 = sB[6*64 + t]; if (u3 > v){ v = u3; gi = 3; }
    atomicOr(&gmS[gi], 1ull << t);
  }

  f4 acc4[4];
  gemm4<7,64>(sB, wsf + W0T, pt4, o4, acc4);
  epi4(acc4, wsf + B0F, o4, sB + 512, pt4);
  __syncthreads();   // s2

  u32 g1lo = (u32)gmS[1], g1hi = (u32)(gmS[1] >> 32);
  u32 g2lo = (u32)gmS[2], g2hi = (u32)(gmS[2] >> 32);
  u32 g3lo = (u32)gmS[3], g3hi = (u32)(gmS[3] >> 32);
  u32 ggpack = 0;
  #pragma unroll
  for (int i = 0; i < 16; ++i){
    int m = i >> 2, r = i & 3;
    int sh = ((m & 1) << 4) + qb + r;
    u32 b1 = ((m < 2 ? g1lo : g1hi) >> sh) & 1u;
    u32 b2 = ((m < 2 ? g2lo : g2hi) >> sh) & 1u;
    u32 b3 = ((m < 2 ? g3lo : g3hi) >> sh) & 1u;
    u32 g = b1 + (b2 << 1) + (b3 << 1) + b3;
    ggpack |= g << (2*i);
  }

  gemm4<64,64>(sB + 512, wsf + W1T, pt4, o4, acc4);  epi4(acc4, wsf + B1F, o4, sB + 4608, pt4);
  __syncthreads();   // s3
  gemm4<64,64>(sB + 4608, wsf + W2T, pt4, o4, acc4); epi4(acc4, wsf + B2F, o4, sB + 512, pt4);
  __syncthreads();   // s4

  f4 acc4b[4];
  gemm4<64,128>(sB + 512, wsf + W3T, pt4, o4, acc4);
  gemm4<64,128>(sB + 512, wsf + W3T, pt4, o4 + 64, acc4b);
  __syncthreads();   // s5

  u16b* F4 = (u16b*)sB;
  storeF4<0>(F4, acc4,  o4, pt4, wsf);
  storeF4<1>(F4, acc4b, o4, pt4, wsf);
  __syncthreads();   // s6

  u64* pslot = pmax + (size_t)(tile & pmask)*(16*1024) + b*1024;
  u32* gslot = gmax + (size_t)(tile & gmask)*4096;
  const char* wbc = (const char*)wb;
  const u32 bvo = (u32)L * 16u;

  short8 bh, bm, bl;
  {
    u32 bofs = ((u32)(w << 4)) * 1024u + bvo;
    bh = *(const short8*)(wbc +           bofs);
    bm = *(const short8*)(wbc + 262144u + bofs);
    bl = *(const short8*)(wbc + 524288u + bofs);
  }
  for (int nti = 0; nti < 16; ++nti){
    const int nt = (w << 4) + nti;
    float bias = wsf[B4F + (nt << 4) + (L & 15)];
    v4f D[4];
    #pragma unroll
    for (int m = 0; m < 4; ++m) D[m] = (v4f)(0.f);
    #pragma unroll
    for (int kc = 0; kc < 4; ++kc){
      short8 cbh = bh, cbm = bm, cbl = bl;
      {
        int knext = (kc == 3) ? 0 : kc + 1;
        int ntn   = (kc == 3) ? nt + 1 : nt;
        u32 bofs = (u32)knext*65536u + (u32)ntn*1024u + bvo;
        bh = *(const short8*)(wbc +           bofs);
        bm = *(const short8*)(wbc + 262144u + bofs);
        bl = *(const short8*)(wbc + 524288u + bofs);
      }
      #pragma unroll
      for (int m = 0; m < 4; ++m){
        const u16b* fb = F4 + (u32)((m*4 + kc)*512 + ((L ^ m) << 3));
        short8 a0 = *(const short8*)(fb);
        short8 a1 = *(const short8*)(fb + 8192);
        short8 a2 = *(const short8*)(fb + 16384);
        D[m] = __builtin_amdgcn_mfma_f32_16x16x32_bf16(a0, cbh, D[m], 0, 0, 0);
        D[m] = __builtin_amdgcn_mfma_f32_16x16x32_bf16(a0, cbm, D[m], 0, 0, 0);
        D[m] = __builtin_amdgcn_mfma_f32_16x16x32_bf16(a1, cbh, D[m], 0, 0, 0);
        D[m] = __builtin_amdgcn_mfma_f32_16x16x32_bf16(a0, cbl, D[m], 0, 0, 0);
        D[m] = __builtin_amdgcn_mfma_f32_16x16x32_bf16(a1, cbm, D[m], 0, 0, 0);
        D[m] = __builtin_amdgcn_mfma_f32_16x16x32_bf16(a2, cbh, D[m], 0, 0, 0);
      }
    }
    float mx = 0.f; int mi = 0;
    float gm0 = 0.f, gm1 = 0.f, gm2 = 0.f, gm3 = 0.f;
    #pragma unroll
    for (int m = 0; m < 4; ++m){
      #pragma unroll
      for (int r = 0; r < 4; ++r){
        int i = m*4 + r;
        float v = fmaxf(D[m][r] + bias, 0.f);
        int pidx = n0 + m*16 + qb + r;
        if (i == 0){ mx = v; mi = pidx; }
        else if (v > mx){ mx = v; mi = pidx; }
        u32 g = (ggpack >> (2*i)) & 3u;
        gm0 = fmaxf(gm0, (g == 0u) ? v : 0.f);
        gm1 = fmaxf(gm1, (g == 1u) ? v : 0.f);
        gm2 = fmaxf(gm2, (g == 2u) ? v : 0.f);
        gm3 = fmaxf(gm3, (g == 3u) ? v : 0.f);
      }
    }
    #pragma unroll
    for (int s = 16; s <= 32; s <<= 1){
      float m2 = __shfl_xor(mx, s);
      int  i2  = __shfl_xor(mi, s);
      if (m2 > mx || (m2 == mx && i2 < mi)){ mx = m2; mi = i2; }
      gm0 = fmaxf(gm0, __shfl_xor(gm0, s));
      gm1 = fmaxf(gm1, __shfl_xor(gm1, s));
      gm2 = fmaxf(gm2, __shfl_xor(gm2, s));
      gm3 = fmaxf(gm3, __shfl_xor(gm3, s));
    }
    if (L < 16){
      int ch = (nt << 4) + L;
      u64 pk = ((u64)__float_as_uint(mx) << 32) | (u64)(0xFFFFFFFFu - (u32)mi);
      atomicMax(pslot + ch, pk);
      if (gm0 > 0.f) atomicMax(gslot + ch,        __float_as_uint(gm0));
      if (gm1 > 0.f) atomicMax(gslot + 1024 + ch, __float_as_uint(gm1));
      if (gm2 > 0.f) atomicMax(gslot + 2048 + ch, __float_as_uint(gm2));
      if (gm3 > 0.f) atomicMax(gslot + 3072 + ch, __float_as_uint(gm3));
    }
  }
}

// ================= SPLIT PATH (needs ws >= ~204 MB) =================
// k_front: L0-3 + split3 -> F4 (LDS) -> copy to global staging + store group masks.
__global__ __launch_bounds__(256, 2) void k_front(const float* __restrict__ pts,
    const float* __restrict__ wsf, float* __restrict__ f4g, u64* __restrict__ ggws)
{
  __shared__ __align__(16) float sB[12288];
  const int t = threadIdx.x;
  const int b = blockIdx.x >> 8;
  const int n0 = (blockIdx.x & 255) * 64;
  const int pt4 = (t & 15) << 2;
  const int o4 = (t >> 4) << 2;
  u64* gmS = (u64*)(sB + 448);

  if (t < 4) gmS[t] = 0ull;
  for (int e = t; e < 7*64; e += 256)
    sB[e] = pts[(b*7 + (e >> 6))*NP + n0 + (e & 63)];
  __syncthreads();
  if (t < 64){
    float v = sB[3*64 + t]; int gi = 0;
    float u1 = sB[4*64 + t]; if (u1 > v){ v = u1; gi = 1; }
    float u2 = sB[5*64 + t]; if (u2 > v){ v = u2; gi = 2; }
    float u3 = sB[6*64 + t]; if (u3 > v){ v = u3; gi = 3; }
    atomicOr(&gmS[gi], 1ull << t);
  }
  f4 acc4[4];
  gemm4<7,64>(sB, wsf + W0T, pt4, o4, acc4);
  epi4(acc4, wsf + B0F, o4, sB + 512, pt4);
  __syncthreads();                                  // s2: masks stable
  if (t < 4) ggws[(size_t)blockIdx.x * 4 + t] = gmS[t];
  gemm4<64,64>(sB + 512, wsf + W1T, pt4, o4, acc4);  epi4(acc4, wsf + B1F, o4, sB + 4608, pt4);
  __syncthreads();
  gemm4<64,64>(sB + 4608, wsf + W2T, pt4, o4, acc4); epi4(acc4, wsf + B2F, o4, sB + 512, pt4);
  __syncthreads();
  f4 acc4b[4];
  gemm4<64,128>(sB + 512, wsf + W3T, pt4, o4, acc4);
  gemm4<64,128>(sB + 512, wsf + W3T, pt4, o4 + 64, acc4b);
  __syncthreads();
  u16b* F4 = (u16b*)sB;
  storeF4<0>(F4, acc4,  o4, pt4, wsf);
  storeF4<1>(F4, acc4b, o4, pt4, wsf);
  __syncthreads();
  // coalesced copy of the 48 KB frag block to global staging
  const f4* s4 = (const f4*)sB;
  f4* dst = (f4*)f4g + (size_t)blockIdx.x * 3072;
  #pragma unroll
  for (int i = 0; i < 12; ++i) dst[i*256 + t] = s4[i*256 + t];
}

// k_l4: pure MFMA kernel. wave = m-tile (A-frags in registers), B double-buffered
// through 24 KB LDS and shared by all 4 waves. 64 nt per block, 1 barrier per nt.
__global__ __launch_bounds__(256, 2) void k_l4(
    const u16b* __restrict__ f4g, const u64* __restrict__ ggws,
    const float* __restrict__ wsf, const u16b* __restrict__ wb,
    u64* __restrict__ pmax, u32* __restrict__ gmax)
{
  __shared__ __align__(16) u16b sBw[2][6144];   // 2 x 12 KB B staging
  const int t = threadIdx.x;
  const int b = blockIdx.x >> 8;
  const int tile = blockIdx.x & 255;
  const int n0 = tile * 64;
  const int m = t >> 6;            // wave id = m-tile
  const int L = t & 63;
  const int qb = (L >> 4) << 2;

  // A-frags for my m: 12 x short8 (48 VGPR), global coalesced loads
  const u16b* fb = f4g + (size_t)blockIdx.x * 24576 + (size_t)((L ^ m) * 8);
  short8 afr[3][4];
  #pragma unroll
  for (int s = 0; s < 3; ++s)
    #pragma unroll
    for (int kc = 0; kc < 4; ++kc)
      afr[s][kc] = *(const short8*)(fb + (u32)(s*8192 + (m*4 + kc)*512));

  // group ids for my 4 D-rows (pt = m*16 + qb + r)
  u64 gw1 = ggws[(size_t)blockIdx.x*4 + 1];
  u64 gw2 = ggws[(size_t)blockIdx.x*4 + 2];
  u64 gw3 = ggws[(size_t)blockIdx.x*4 + 3];
  u32 gg4 = 0;
  #pragma unroll
  for (int r = 0; r < 4; ++r){
    int pt = m*16 + qb + r;
    u32 g = (u32)((gw1 >> pt) & 1) + 2u*(u32)((gw2 >> pt) & 1) + 3u*(u32)((gw3 >> pt) & 1);
    gg4 |= g << (2*r);
  }

  u64* pslot = pmax + (size_t)(tile & 7)*(16*1024) + b*1024;
  u32* gslot = gmax + (size_t)(tile & 15)*4096;

  // B staging helpers: per nt slice = [c = s*4+kc][64 f4], thread t copies 3 f4
  const f4* wb4 = (const f4*)wb;
  f4 stg[3];
  {
    int nt = 0;
    #pragma unroll
    for (int k = 0; k < 3; ++k){
      int i = t + (k << 8), c = i >> 6, off = i & 63;
      stg[k] = wb4[(size_t)((c >> 2)*16384 + (c & 3)*4096 + nt*64 + off)];
    }
    f4* l4 = (f4*)sBw[0];
    #pragma unroll
    for (int k = 0; k < 3; ++k) l4[t + (k << 8)] = stg[k];
  }
  __syncthreads();

  for (int nt = 0; nt < 64; ++nt){
    if (nt < 63){                                  // prefetch next B slice to regs
      #pragma unroll
      for (int k = 0; k < 3; ++k){
        int i = t + (k << 8), c = i >> 6, off = i & 63;
        stg[k] = wb4[(size_t)((c >> 2)*16384 + (c & 3)*4096 + (nt + 1)*64 + off)];
      }
    }
    float bias = wsf[B4F + (nt << 4) + (L & 15)];
    const u16b* bbuf = sBw[nt & 1];
    v4f D = (v4f)(0.f);
    #pragma unroll
    for (int kc = 0; kc < 4; ++kc){
      short8 bh = *(const short8*)(bbuf + (u32)((0*4 + kc)*512 + L*8));
      short8 bm = *(const short8*)(bbuf + (u32)((1*4 + kc)*512 + L*8));
      short8 bl = *(const short8*)(bbuf + (u32)((2*4 + kc)*512 + L*8));
      D = __builtin_amdgcn_mfma_f32_16x16x32_bf16(afr[0][kc], bh, D, 0, 0, 0);
      D = __builtin_amdgcn_mfma_f32_16x16x32_bf16(afr[0][kc], bm, D, 0, 0, 0);
      D = __builtin_amdgcn_mfma_f32_16x16x32_bf16(afr[1][kc], bh, D, 0, 0, 0);
      D = __builtin_amdgcn_mfma_f32_16x16x32_bf16(afr[0][kc], bl, D, 0, 0, 0);
      D = __builtin_amdgcn_mfma_f32_16x16x32_bf16(afr[1][kc], bm, D, 0, 0, 0);
      D = __builtin_amdgcn_mfma_f32_16x16x32_bf16(afr[2][kc], bh, D, 0, 0, 0);
    }
    // epilogue: 4 D-rows of my m-tile
    float mx = 0.f; int mi = 0;
    float gm0 = 0.f, gm1 = 0.f, gm2 = 0.f, gm3 = 0.f;
    #pragma unroll
    for (int r = 0; r < 4; ++r){
      float v = fmaxf(D[r] + bias, 0.f);
      int pidx = n0 + m*16 + qb + r;
      if (r == 0){ mx = v; mi = pidx; }
      else if (v > mx){ mx = v; mi = pidx; }
      u32 g = (gg4 >> (2*r)) & 3u;
      gm0 = fmaxf(gm0, (g == 0u) ? v : 0.f);
      gm1 = fmaxf(gm1, (g == 1u) ? v : 0.f);
      gm2 = fmaxf(gm2, (g == 2u) ? v : 0.f);
      gm3 = fmaxf(gm3, (g == 3u) ? v : 0.f);
    }
    #pragma unroll
    for (int s = 16; s <= 32; s <<= 1){
      float m2 = __shfl_xor(mx, s);
      int  i2  = __shfl_xor(mi, s);
      if (m2 > mx || (m2 == mx && i2 < mi)){ mx = m2; mi = i2; }
      gm0 = fmaxf(gm0, __shfl_xor(gm0, s));
      gm1 = fmaxf(gm1, __shfl_xor(gm1, s));
      gm2 = fmaxf(gm2, __shfl_xor(gm2, s));
      gm3 = fmaxf(gm3, __shfl_xor(gm3, s));
    }
    if (L < 16){
      int ch = (nt << 4) + L;
      u64 pk = ((u64)__float_as_uint(mx) << 32) | (u64)(0xFFFFFFFFu - (u32)mi);
      atomicMax(pslot + ch, pk);
      if (gm0 > 0.f) atomicMax(gslot + ch,        __float_as_uint(gm0));
      if (gm1 > 0.f) atomicMax(gslot + 1024 + ch, __float_as_uint(gm1));
      if (gm2 > 0.f) atomicMax(gslot + 2048 + ch, __float_as_uint(gm2));
      if (gm3 > 0.f) atomicMax(gslot + 3072 + ch, __float_as_uint(gm3));
    }
    if (nt < 63){                                  // publish next B slice
      f4* l4 = (f4*)sBw[(nt + 1) & 1];
      #pragma unroll
      for (int k = 0; k < 3; ++k) l4[t + (k << 8)] = stg[k];
    }
    __syncthreads();
  }
}

// ---------------- fold slots; emit max_indices (fp32) + gf + gcf ----------------
__global__ __launch_bounds__(256) void k_reduce(float* __restrict__ wsf, float* __restrict__ out,
                                                u32 pmax_off, u32 gmax_off, int P, int G)
{
  int e = blockIdx.x * 256 + threadIdx.x;          // grid 80 -> 20480
  u64* pmax = (u64*)((char*)wsf + pmax_off);
  u32* gmax = (u32*)((char*)wsf + gmax_off);
  if (e < 16384){
    u64 m = 0ull;
    for (int s = 0; s < P; ++s){ u64 v = pmax[s*16384 + e]; if (v > m) m = v; }
    float val = __uint_as_float((u32)(m >> 32));
    u32 idx = 0xFFFFFFFFu - (u32)(m & 0xFFFFFFFFull);
    wsf[GFO + e] = val;
    out[4096 + e] = (float)idx;
  } else if (e < 20480){
    int e2 = e - 16384;
    u32 mg = 0u;
    for (int s = 0; s < G; ++s){ u32 v = gmax[s*4096 + e2]; if (v > mg) mg = v; }
    wsf[GCFO + e2] = __uint_as_float(mg);
  }
}

// ---------------- small MLPs: one wave per dot product ----------------
__global__ __launch_bounds__(256) void k_mlp1(float* __restrict__ wsf,
    const float* __restrict__ wg0, const float* __restrict__ bg0,
    const float* __restrict__ wgr0, const float* __restrict__ bgr0)
{
  int wid = (blockIdx.x * 256 + threadIdx.x) >> 6;
  int lane = threadIdx.x & 63;
  if (wid < 8192){
    int b = wid >> 9, o = wid & 511;
    const float* gf = wsf + GFO + b*1024;
    float s = 0.f;
    #pragma unroll
    for (int i = 0; i < 16; ++i){ int k = lane + (i << 6); s = fmaf(gf[k], wg0[o*1024 + k], s); }
    for (int off = 32; off; off >>= 1) s += __shfl_down(s, off);
    if (lane == 0) wsf[OF1O + b*512 + o] = fmaxf(s + bg0[o], 0.f);
  } else if (wid < 8704){
    int o = wid - 8192;
    const float* gcf = wsf + GCFO;
    float s = 0.f;
    #pragma unroll 8
    for (int i = 0; i < 64; ++i){ int k = lane + (i << 6); s = fmaf(gcf[k], wgr0[o*4096 + k], s); }
    for (int off = 32; off; off >>= 1) s += __shfl_down(s, off);
    if (lane == 0) wsf[GR1O + o] = fmaxf(s + bgr0[o], 0.f);
  }
}

__global__ __launch_bounds__(256) void k_mlp2(const float* __restrict__ wsf,
    const float* __restrict__ wg1, const float* __restrict__ bg1,
    const float* __restrict__ wgr1, const float* __restrict__ bgr1,
    float* __restrict__ out)
{
  int wid = (blockIdx.x * 256 + threadIdx.x) >> 6;
  int lane = threadIdx.x & 63;
  if (wid < 2048){
    int b = wid >> 7, o = wid & 127;
    const float* of1 = wsf + OF1O + b*512;
    float s = 0.f;
    #pragma unroll
    for (int i = 0; i < 8; ++i){ int k = lane + (i << 6); s = fmaf(of1[k], wg1[o*512 + k], s); }
    for (int off = 32; off; off >>= 1) s += __shfl_down(s, off);
    if (lane == 0) out[b*256 + 128 + o] = fmaxf(s + bg1[o], 0.f);
  } else if (wid < 2176){
    int o = wid - 2048;
    const float* gr1 = wsf + GR1O;
    float s = 0.f;
    #pragma unroll
    for (int i = 0; i < 8; ++i){ int k = lane + (i << 6); s = fmaf(gr1[k], wgr1[o*512 + k], s); }
    for (int off = 32; off; off >>= 1) s += __shfl_down(s, off);
    if (lane == 0){
      float r = fmaxf(s + bgr1[o], 0.f);
      for (int bb = 0; bb < 16; ++bb) out[bb*256 + o] = r;
    }
  }
}

extern "C" void kernel_launch(void* const* d_in, const int* in_sizes, int n_in,
                              void* d_out, int out_size, void* d_ws, size_t ws_size,
                              hipStream_t stream)
{
  const float* pts  = (const float*)d_in[0];
  const float* wl0  = (const float*)d_in[1];  const float* bl0 = (const float*)d_in[2];
  const float* wl1  = (const float*)d_in[3];  const float* bl1 = (const float*)d_in[4];
  const float* wl2  = (const float*)d_in[5];  const float* bl2 = (const float*)d_in[6];
  const float* wl3  = (const float*)d_in[7];  const float* bl3 = (const float*)d_in[8];
  const float* wl4  = (const float*)d_in[9];  const float* bl4 = (const float*)d_in[10];
  const float* wg0  = (const float*)d_in[11]; const float* bg0 = (const float*)d_in[12];
  const float* wg1  = (const float*)d_in[13]; const float* bg1 = (const float*)d_in[14];
  const float* wgr0 = (const float*)d_in[15]; const float* bgr0 = (const float*)d_in[16];
  const float* wgr1 = (const float*)d_in[17]; const float* bgr1 = (const float*)d_in[18];
  float* wsf = (float*)d_ws;
  float* out = (float*)d_out;

  // split-path layout: pmax(8 slots) | gmax(16) | Wb | gg masks | F4 staging (192 MB)
  const size_t SPLIT_MIN = (size_t)FIXED_BYTES + 1048576 + 262144 + 786432 + 131072
                         + (size_t)4096 * 49152;   // ~203.7 MB
  if (ws_size >= SPLIT_MIN){
    u32 pmax_off = FIXED_BYTES;
    u32 gmax_off = pmax_off + 8u * 131072u;
    u32 wb_off   = gmax_off + 16u * 16384u;
    u32 gg_off   = wb_off + 786432u;
    u32 f4g_off  = gg_off + 131072u;
    k_prep<<<dim3(1024), dim3(256), 0, stream>>>(wl0, wl1, wl2, wl3, wl4,
        bl0, bl1, bl2, bl3, bl4, wsf, pmax_off, gmax_off, wb_off, 8, 16);
    k_front<<<dim3(4096), dim3(256), 0, stream>>>(pts, wsf,
        (float*)((char*)d_ws + f4g_off), (u64*)((char*)d_ws + gg_off));
    k_l4<<<dim3(4096), dim3(256), 0, stream>>>(
        (const u16b*)((char*)d_ws + f4g_off), (const u64*)((char*)d_ws + gg_off),
        wsf, (const u16b*)((char*)d_ws + wb_off),
        (u64*)((char*)d_ws + pmax_off), (u32*)((char*)d_ws + gmax_off));
    k_reduce<<<dim3(80), dim3(256), 0, stream>>>(wsf, out, pmax_off, gmax_off, 8, 16);
  } else {
    int P, G;
    if      (ws_size >= 2400000) { P = 8; G = 16; }
    else if (ws_size >= 1700000) { P = 4; G = 8;  }
    else if (ws_size >= 1360000) { P = 2; G = 4;  }
    else                         { P = 1; G = 2;  }
    u32 pmax_off = FIXED_BYTES;
    u32 gmax_off = pmax_off + (u32)P * 131072u;
    u32 wb_off   = gmax_off + (u32)G * 16384u;
    k_prep<<<dim3(1024), dim3(256), 0, stream>>>(wl0, wl1, wl2, wl3, wl4,
        bl0, bl1, bl2, bl3, bl4, wsf, pmax_off, gmax_off, wb_off, P, G);
    k_main_r10<<<dim3(4096), dim3(256), 0, stream>>>(pts, wsf,
        (const u16b*)((char*)d_ws + wb_off),
        (u64*)((char*)d_ws + pmax_off), (u32*)((char*)d_ws + gmax_off), P-1, G-1);
    k_reduce<<<dim3(80), dim3(256), 0, stream>>>(wsf, out, pmax_off, gmax_off, P, G);
  }
  k_mlp1<<<dim3(2176), dim3(256), 0, stream>>>(wsf, wg0, bg0, wgr0, bgr0);
  k_mlp2<<<dim3(544), dim3(256), 0, stream>>>(wsf, wg1, bg1, wgr1, bgr1, out);
}